// Round 3
// baseline (155.259 us; speedup 1.0000x reference)
//
#include <hip/hip_runtime.h>

// x: (32, 3, 512, 512) fp32, channel plane stride HW = 512*512 = 262144.
// out: (32, 1, 512, 512) fp32.
// Streaming memory-bound: 1 thread = 8 pixels (2x float4 per plane),
// 6 outstanding 16B loads per thread, non-temporal (no reuse).

#define HW    262144          // 512*512
#define NPIX  8388608         // 32*HW (output elements)

// native vector type — __builtin_nontemporal_* rejects HIP's class-based float4
typedef float vfloat4 __attribute__((ext_vector_type(4)));

__device__ __forceinline__ vfloat4 ntload4(const float* p) {
    return __builtin_nontemporal_load((const vfloat4*)p);
}
__device__ __forceinline__ void ntstore4(float* p, vfloat4 v) {
    __builtin_nontemporal_store(v, (vfloat4*)p);
}

__device__ __forceinline__ float hue_px(float r, float g, float b, float w, float bb) {
    float cmax  = fmaxf(r, fmaxf(g, b));
    float cmin  = fminf(r, fminf(g, b));
    float delta = cmax - cmin;
    float sd  = (delta == 0.0f) ? 1.0f : delta;
    float inv = 1.0f / sd;
    float t0 = (g - b) * inv;
    t0 = (t0 < 0.0f) ? (t0 + 6.0f) : t0;          // mod(t,6), t in [-1,1]
    float t1 = (b - r) * inv + 2.0f;
    float t2 = (r - g) * inv + 4.0f;
    // argmax first-occurrence: 0 if r==cmax, else 1 if g==cmax, else 2
    float hue = (r == cmax) ? t0 : ((g == cmax) ? t1 : t2);
    hue = (delta == 0.0f) ? 0.0f : hue;
    return (hue * 0.16666666666666666f) * w + bb; // hue/6 * W + b
}

__global__ __launch_bounds__(256) void HBEMD_F_67156108640795_kernel(
    const float* __restrict__ x,
    const float* __restrict__ Wp,
    const float* __restrict__ Bp,
    float* __restrict__ out)
{
    int v = blockIdx.x * blockDim.x + threadIdx.x;   // 8-pixel group index
    int o = v << 3;                                  // pixel index (multiple of 8)

    int n = o >> 18;                                 // o / HW
    int p = o & (HW - 1);                            // o % HW (8-aligned)
    const float* base = x + (size_t)n * (3 * HW) + p;

    // issue all 6 loads back-to-back for max memory-level parallelism
    vfloat4 r0 = ntload4(base);
    vfloat4 r1 = ntload4(base + 4);
    vfloat4 g0 = ntload4(base + HW);
    vfloat4 g1 = ntload4(base + HW + 4);
    vfloat4 b0 = ntload4(base + 2 * HW);
    vfloat4 b1 = ntload4(base + 2 * HW + 4);

    float w  = Wp[0];
    float bb = Bp[0];

    vfloat4 o0, o1;
    o0.x = hue_px(r0.x, g0.x, b0.x, w, bb);
    o0.y = hue_px(r0.y, g0.y, b0.y, w, bb);
    o0.z = hue_px(r0.z, g0.z, b0.z, w, bb);
    o0.w = hue_px(r0.w, g0.w, b0.w, w, bb);
    o1.x = hue_px(r1.x, g1.x, b1.x, w, bb);
    o1.y = hue_px(r1.y, g1.y, b1.y, w, bb);
    o1.z = hue_px(r1.z, g1.z, b1.z, w, bb);
    o1.w = hue_px(r1.w, g1.w, b1.w, w, bb);

    ntstore4(out + o, o0);
    ntstore4(out + o + 4, o1);
}

extern "C" void kernel_launch(void* const* d_in, const int* in_sizes, int n_in,
                              void* d_out, int out_size, void* d_ws, size_t ws_size,
                              hipStream_t stream) {
    const float* x  = (const float*)d_in[0];
    const float* W  = (const float*)d_in[1];
    const float* b  = (const float*)d_in[2];
    float* out = (float*)d_out;

    const int threads = 256;
    const int blocks = NPIX / (8 * threads);   // 4096 exactly
    HBEMD_F_67156108640795_kernel<<<blocks, threads, 0, stream>>>(x, W, b, out);
}